// Round 2
// baseline (171.860 us; speedup 1.0000x reference)
//
#include <hip/hip_runtime.h>
#include <math.h>

// ---------------------------------------------------------------------------
// Kernel 1: E_k = expm(t_k * (M + M0)) via scaling-and-squaring + 12-term
// Taylor. 3x3 only (homogeneous row/col of the 4x4 never contributes since
// x_pad's last coord is 0 and A's last row is 0). One thread per t.
// ---------------------------------------------------------------------------
__global__ void expm_kernel(const float* __restrict__ t,
                            const float* __restrict__ M,
                            const float* __restrict__ M0,
                            float* __restrict__ E_out,
                            int T) {
    int k = blockIdx.x * blockDim.x + threadIdx.x;
    if (k >= T) return;

    float tk = t[k];
    float B[9];
#pragma unroll
    for (int i = 0; i < 9; ++i) B[i] = tk * (M[i] + M0[i]);

    float norm = 0.f;
#pragma unroll
    for (int i = 0; i < 3; ++i) {
        float rs = fabsf(B[i * 3]) + fabsf(B[i * 3 + 1]) + fabsf(B[i * 3 + 2]);
        norm = fmaxf(norm, rs);
    }
    int s = 0;
    while (norm > 0.25f && s < 40) { norm *= 0.5f; ++s; }
    float scale = exp2f((float)(-s));
#pragma unroll
    for (int i = 0; i < 9; ++i) B[i] *= scale;

    float P[9], E[9];
#pragma unroll
    for (int i = 0; i < 9; ++i) { P[i] = (i % 4 == 0) ? 1.f : 0.f; E[i] = P[i]; }
    for (int n = 1; n <= 12; ++n) {
        float inv = 1.0f / (float)n;
        float Q[9];
#pragma unroll
        for (int i = 0; i < 3; ++i)
#pragma unroll
            for (int j = 0; j < 3; ++j)
                Q[i * 3 + j] = (P[i * 3 + 0] * B[0 * 3 + j] +
                                P[i * 3 + 1] * B[1 * 3 + j] +
                                P[i * 3 + 2] * B[2 * 3 + j]) * inv;
#pragma unroll
        for (int i = 0; i < 9; ++i) { P[i] = Q[i]; E[i] += Q[i]; }
    }
    for (int q = 0; q < s; ++q) {
        float Q[9];
#pragma unroll
        for (int i = 0; i < 3; ++i)
#pragma unroll
            for (int j = 0; j < 3; ++j)
                Q[i * 3 + j] = E[i * 3 + 0] * E[0 * 3 + j] +
                               E[i * 3 + 1] * E[1 * 3 + j] +
                               E[i * 3 + 2] * E[2 * 3 + j];
#pragma unroll
        for (int i = 0; i < 9; ++i) E[i] = Q[i];
    }

#pragma unroll
    for (int i = 0; i < 9; ++i) E_out[k * 9 + i] = E[i];
}

// ---------------------------------------------------------------------------
// Kernel 2: out[t, n, i] = sum_j E_t[i][j] * x[n][j]
// x tile staged in LDS ONCE per block; inner loop over a t-range writes
// TSEG output slabs. Read traffic: TSPLIT * |x| = ~24 MB total (vs 384 MB
// when every (tile,t) block restaged x). Writes stay 384 MB -> write-bound.
// Per-t slab base is 16B-aligned (N*3 and TILE_N*3 divisible by 4).
// ---------------------------------------------------------------------------
#define TILE_N 1024
#define TSPLIT 4
#define TPB 256

__global__ __launch_bounds__(TPB) void apply_kernel(const float* __restrict__ x,
                                                    const float* __restrict__ E_all,
                                                    float* __restrict__ out,
                                                    int N, int T) {
    __shared__ __align__(16) float xs[TILE_N * 3];

    const int tid  = threadIdx.x;
    const int tile = blockIdx.x;
    const int tseg = blockIdx.y;
    const int tlen = (T + TSPLIT - 1) / TSPLIT;
    const int t0   = tseg * tlen;
    const int t1   = min(T, t0 + tlen);

    const long n0   = (long)tile * TILE_N;
    const int  rows = min(TILE_N, (int)(N - n0));
    const int  nflt = rows * 3;
    const int  nvec = nflt >> 2;          // full float4 count
    const int  rem0 = nvec << 2;

    // stage x tile once (coalesced float4; n0*3 divisible by 4 -> 16B aligned)
    const float* xsrc = x + n0 * 3;
    for (int v = tid; v < nvec; v += TPB)
        reinterpret_cast<float4*>(xs)[v] =
            reinterpret_cast<const float4*>(xsrc)[v];
    for (int v = rem0 + tid; v < nflt; v += TPB)
        xs[v] = xsrc[v];
    __syncthreads();

    for (int tt = t0; tt < t1; ++tt) {
        float E[9];
#pragma unroll
        for (int i = 0; i < 9; ++i) E[i] = E_all[tt * 9 + i];

        float* dst = out + ((long)tt * N + n0) * 3;
        for (int v = tid; v < nvec; v += TPB) {
            const int e0 = v << 2;
            float4 r;
            float* rp = &r.x;
#pragma unroll
            for (int c = 0; c < 4; ++c) {
                const int e = e0 + c;
                const int n = e / 3;          // magic-mul
                const int i = e - n * 3;
                rp[c] = E[i * 3 + 0] * xs[n * 3 + 0] +
                        E[i * 3 + 1] * xs[n * 3 + 1] +
                        E[i * 3 + 2] * xs[n * 3 + 2];
            }
            reinterpret_cast<float4*>(dst)[v] = r;
        }
        for (int v = rem0 + tid; v < nflt; v += TPB) {
            const int n = v / 3;
            const int i = v - n * 3;
            dst[v] = E[i * 3 + 0] * xs[n * 3 + 0] +
                     E[i * 3 + 1] * xs[n * 3 + 1] +
                     E[i * 3 + 2] * xs[n * 3 + 2];
        }
    }
}

extern "C" void kernel_launch(void* const* d_in, const int* in_sizes, int n_in,
                              void* d_out, int out_size, void* d_ws, size_t ws_size,
                              hipStream_t stream) {
    const float* x  = (const float*)d_in[0];   // (N, 3)
    const float* t  = (const float*)d_in[1];   // (T,)
    const float* M  = (const float*)d_in[2];   // (3, 3)
    const float* M0 = (const float*)d_in[3];   // (3, 3)
    // d_in[4] = b (3,) — never contributes: homogeneous coord of x_pad is 0.

    const int N = in_sizes[0] / 3;
    const int T = in_sizes[1];

    float* E_ws = (float*)d_ws;                 // T*9 floats
    float* out  = (float*)d_out;

    expm_kernel<<<(T + 63) / 64, 64, 0, stream>>>(t, M, M0, E_ws, T);

    dim3 grid((N + TILE_N - 1) / TILE_N, TSPLIT);
    apply_kernel<<<grid, TPB, 0, stream>>>(x, E_ws, out, N, T);
}

// Round 3
// 149.822 us; speedup vs baseline: 1.1471x; 1.1471x over previous
//
#include <hip/hip_runtime.h>
#include <math.h>

typedef float f4 __attribute__((ext_vector_type(4)));

// ---------------------------------------------------------------------------
// Kernel 1: E_k = expm(t_k * (M + M0)) via scaling-and-squaring + 12-term
// Taylor. 3x3 only (homogeneous row/col of the 4x4 never contributes since
// x_pad's last coord is 0 and A's last row is 0). One thread per t.
// ---------------------------------------------------------------------------
__global__ void expm_kernel(const float* __restrict__ t,
                            const float* __restrict__ M,
                            const float* __restrict__ M0,
                            float* __restrict__ E_out,
                            int T) {
    int k = blockIdx.x * blockDim.x + threadIdx.x;
    if (k >= T) return;

    float tk = t[k];
    float B[9];
#pragma unroll
    for (int i = 0; i < 9; ++i) B[i] = tk * (M[i] + M0[i]);

    float norm = 0.f;
#pragma unroll
    for (int i = 0; i < 3; ++i) {
        float rs = fabsf(B[i * 3]) + fabsf(B[i * 3 + 1]) + fabsf(B[i * 3 + 2]);
        norm = fmaxf(norm, rs);
    }
    int s = 0;
    while (norm > 0.25f && s < 40) { norm *= 0.5f; ++s; }
    float scale = exp2f((float)(-s));
#pragma unroll
    for (int i = 0; i < 9; ++i) B[i] *= scale;

    float P[9], E[9];
#pragma unroll
    for (int i = 0; i < 9; ++i) { P[i] = (i % 4 == 0) ? 1.f : 0.f; E[i] = P[i]; }
    for (int n = 1; n <= 12; ++n) {
        float inv = 1.0f / (float)n;
        float Q[9];
#pragma unroll
        for (int i = 0; i < 3; ++i)
#pragma unroll
            for (int j = 0; j < 3; ++j)
                Q[i * 3 + j] = (P[i * 3 + 0] * B[0 * 3 + j] +
                                P[i * 3 + 1] * B[1 * 3 + j] +
                                P[i * 3 + 2] * B[2 * 3 + j]) * inv;
#pragma unroll
        for (int i = 0; i < 9; ++i) { P[i] = Q[i]; E[i] += Q[i]; }
    }
    for (int q = 0; q < s; ++q) {
        float Q[9];
#pragma unroll
        for (int i = 0; i < 3; ++i)
#pragma unroll
            for (int j = 0; j < 3; ++j)
                Q[i * 3 + j] = E[i * 3 + 0] * E[0 * 3 + j] +
                               E[i * 3 + 1] * E[1 * 3 + j] +
                               E[i * 3 + 2] * E[2 * 3 + j];
#pragma unroll
        for (int i = 0; i < 9; ++i) E[i] = Q[i];
    }

#pragma unroll
    for (int i = 0; i < 9; ++i) E_out[k * 9 + i] = E[i];
}

// ---------------------------------------------------------------------------
// Kernel 2 (round-1 structure + NONTEMPORAL stores):
//   out[t, n, i] = sum_j E_t[i][j] * x[n][j]
// grid = (tiles, T); consecutive blocks write consecutive addresses (write
// locality preserved — round 2 showed scattering these costs 2x). The `nt`
// stores stream past L2/L3 so the 384 MB write stream stops evicting x
// (6 MB) from the 256 MB L3 -> x re-reads become L3 hits, HBM ~ writes only.
// ---------------------------------------------------------------------------
#define TILE_N 1024
#define TPB 256

__global__ __launch_bounds__(TPB) void apply_kernel(const float* __restrict__ x,
                                                    const float* __restrict__ E_all,
                                                    float* __restrict__ out,
                                                    int N) {
    __shared__ __align__(16) float xs[TILE_N * 3];

    const int tid  = threadIdx.x;
    const int tile = blockIdx.x;
    const int tt   = blockIdx.y;

    const long n0   = (long)tile * TILE_N;
    const int  rows = min(TILE_N, (int)(N - n0));
    const int  nflt = rows * 3;
    const int  nvec = nflt >> 2;          // full float4 count
    const int  rem0 = nvec << 2;

    // E for this t -> registers (uniform broadcast)
    float E[9];
#pragma unroll
    for (int i = 0; i < 9; ++i) E[i] = E_all[tt * 9 + i];

    // stage x tile (coalesced float4; n0*3 divisible by 4 -> 16B aligned)
    const float* xsrc = x + n0 * 3;
    for (int v = tid; v < nvec; v += TPB)
        reinterpret_cast<f4*>(xs)[v] =
            reinterpret_cast<const f4*>(xsrc)[v];
    for (int v = rem0 + tid; v < nflt; v += TPB)
        xs[v] = xsrc[v];
    __syncthreads();

    float* dst = out + ((long)tt * N + n0) * 3;
    for (int v = tid; v < nvec; v += TPB) {
        const int e0 = v << 2;
        f4 r;
#pragma unroll
        for (int c = 0; c < 4; ++c) {
            const int e = e0 + c;
            const int n = e / 3;          // magic-mul, small ints
            const int i = e - n * 3;
            r[c] = E[i * 3 + 0] * xs[n * 3 + 0] +
                   E[i * 3 + 1] * xs[n * 3 + 1] +
                   E[i * 3 + 2] * xs[n * 3 + 2];
        }
        __builtin_nontemporal_store(r, reinterpret_cast<f4*>(dst) + v);
    }
    for (int v = rem0 + tid; v < nflt; v += TPB) {
        const int n = v / 3;
        const int i = v - n * 3;
        float val = E[i * 3 + 0] * xs[n * 3 + 0] +
                    E[i * 3 + 1] * xs[n * 3 + 1] +
                    E[i * 3 + 2] * xs[n * 3 + 2];
        __builtin_nontemporal_store(val, dst + v);
    }
}

extern "C" void kernel_launch(void* const* d_in, const int* in_sizes, int n_in,
                              void* d_out, int out_size, void* d_ws, size_t ws_size,
                              hipStream_t stream) {
    const float* x  = (const float*)d_in[0];   // (N, 3)
    const float* t  = (const float*)d_in[1];   // (T,)
    const float* M  = (const float*)d_in[2];   // (3, 3)
    const float* M0 = (const float*)d_in[3];   // (3, 3)
    // d_in[4] = b (3,) — never contributes: homogeneous coord of x_pad is 0.

    const int N = in_sizes[0] / 3;
    const int T = in_sizes[1];

    float* E_ws = (float*)d_ws;                 // T*9 floats
    float* out  = (float*)d_out;

    expm_kernel<<<(T + 63) / 64, 64, 0, stream>>>(t, M, M0, E_ws, T);

    dim3 grid((N + TILE_N - 1) / TILE_N, T);
    apply_kernel<<<grid, TPB, 0, stream>>>(x, E_ws, out, N);
}